// Round 1
// baseline (144.445 us; speedup 1.0000x reference)
//
#include <hip/hip_runtime.h>
#include <math.h>

// NeRF renderer: B=1,Q=4,N=4096 rays; 64 coarse + 64 fine samples; HIDDEN=64.
// One wave per ray, 4 rays per 256-thread block.

__device__ __forceinline__ float softplus_f(float x) {
    // identical to jax.nn.softplus = logaddexp(x, 0)
    return fmaxf(x, 0.0f) + log1pf(expf(-fabsf(x)));
}

__device__ __forceinline__ float density_eval(
    float px, float py, float pz,
    const float* __restrict__ W1, const float* __restrict__ b1,
    const float* __restrict__ ws, float bs)
{
    float acc = bs;
    for (int j = 0; j < 64; ++j) {
        float h = fmaf(px, W1[j], fmaf(py, W1[64 + j], fmaf(pz, W1[128 + j], b1[j])));
        h = fmaxf(h, 0.0f);
        acc = fmaf(h, ws[j], acc);
    }
    return softplus_f(acc);
}

__device__ __forceinline__ void color_eval(
    float px, float py, float pz, float dx, float dy, float dz,
    const float* __restrict__ Wc1, const float* __restrict__ bc1,
    const float* __restrict__ Wc2, const float* __restrict__ bc2,
    float& r, float& g, float& b)
{
    float ar = 0.0f, ag = 0.0f, ab = 0.0f;
    for (int j = 0; j < 64; ++j) {
        float h = fmaf(px, Wc1[j],
                  fmaf(py, Wc1[64 + j],
                  fmaf(pz, Wc1[128 + j],
                  fmaf(dx, Wc1[192 + j],
                  fmaf(dy, Wc1[256 + j],
                  fmaf(dz, Wc1[320 + j], bc1[j]))))));
        h = fmaxf(h, 0.0f);
        ar = fmaf(h, Wc2[j * 3 + 0], ar);
        ag = fmaf(h, Wc2[j * 3 + 1], ag);
        ab = fmaf(h, Wc2[j * 3 + 2], ab);
    }
    r = 1.0f / (1.0f + expf(-(ar + bc2[0])));
    g = 1.0f / (1.0f + expf(-(ag + bc2[1])));
    b = 1.0f / (1.0f + expf(-(ab + bc2[2])));
}

struct RayLds {
    float z[64];     // coarse z
    float nz[64];    // fine z
    float cdf[64];   // cdf[0..62]
    float bins[64];  // z_mid[0..62]
    float zall[128]; // merged z
    float sall[128]; // merged sigma
};

__global__ __launch_bounds__(256) void nerf_render_kernel(
    const float* __restrict__ rays_o, const float* __restrict__ rays_d,
    const float* __restrict__ W1, const float* __restrict__ b1,
    const float* __restrict__ w_sigma, const float* __restrict__ b_sigma,
    const float* __restrict__ Wc1, const float* __restrict__ bc1,
    const float* __restrict__ Wc2, const float* __restrict__ bc2,
    float* __restrict__ out, int nrays)
{
    __shared__ RayLds L[4];
    const int wave = threadIdx.x >> 6;
    const int lane = threadIdx.x & 63;
    int ray = blockIdx.x * 4 + wave;
    const bool valid = ray < nrays;
    if (!valid) ray = 0;
    RayLds& R = L[wave];

    const float ox = rays_o[ray * 3 + 0], oy = rays_o[ray * 3 + 1], oz = rays_o[ray * 3 + 2];
    const float dx = rays_d[ray * 3 + 0], dy = rays_d[ray * 3 + 1], dz = rays_d[ray * 3 + 2];
    const float bsig = b_sigma[0];

    // ---- near/far vs cube [-1,1]^3 (slab test, faithful incl. +1e-15) ----
    float ivx = 1.0f / (dx + 1e-15f), ivy = 1.0f / (dy + 1e-15f), ivz = 1.0f / (dz + 1e-15f);
    float tax = (-1.0f - ox) * ivx, tbx = (1.0f - ox) * ivx;
    float tay = (-1.0f - oy) * ivy, tby = (1.0f - oy) * ivy;
    float taz = (-1.0f - oz) * ivz, tbz = (1.0f - oz) * ivz;
    float nearv = fmaxf(fmaxf(fminf(tax, tbx), fminf(tay, tby)), fminf(taz, tbz));
    float farv  = fminf(fminf(fmaxf(tax, tbx), fmaxf(tay, tby)), fmaxf(taz, tbz));
    if (farv < nearv) { nearv = 1e9f; farv = 1e9f; }
    nearv = fmaxf(nearv, 0.5f);
    const float sample_dist = (farv - nearv) * (1.0f / 64.0f);

    // ---- coarse samples: z_i = near + (far-near)*i/63, density MLP ----
    const float z = nearv + (farv - nearv) * ((float)lane * (1.0f / 63.0f));
    const float sig = density_eval(ox + dx * z, oy + dy * z, oz + dz * z, W1, b1, w_sigma, bsig);

    R.z[lane] = z;

    float znext = __shfl_down(z, 1);
    float delta = (lane < 63) ? (znext - z) : sample_dist;
    float e = expf(-delta * sig);
    float alpha = 1.0f - e;
    float T = e + 1e-15f;               // 1 - alpha + 1e-15

    // exclusive prefix-product of T across the wave
    float pincl = T;
    #pragma unroll
    for (int off = 1; off < 64; off <<= 1) {
        float v = __shfl_up(pincl, off);
        if (lane >= off) pincl *= v;
    }
    float pexcl = __shfl_up(pincl, 1);
    if (lane == 0) pexcl = 1.0f;
    const float wgt = alpha * pexcl;    // coarse weights

    // ---- pdf/cdf over weights[1..62]; bins = z_mid[0..62] ----
    float val = (lane >= 1 && lane <= 62) ? (wgt + 1e-5f) : 0.0f;
    float sincl = val;
    #pragma unroll
    for (int off = 1; off < 64; off <<= 1) {
        float v = __shfl_up(sincl, off);
        if (lane >= off) sincl += v;
    }
    const float wsum = __shfl(sincl, 63);
    if (lane < 63) {
        R.cdf[lane]  = sincl / wsum;        // cdf[0]=0, cdf[k]=sum pdf[<k]
        R.bins[lane] = z + 0.5f * delta;    // z_mid
    }
    __syncthreads();

    // ---- deterministic inverse-CDF sampling: u_k = (k+0.5)/64 ----
    const float u = ((float)lane + 0.5f) * (1.0f / 64.0f);
    int ind = 0;
    for (int idx = 0; idx < 63; ++idx) ind += (R.cdf[idx] <= u) ? 1 : 0;  // searchsorted right
    int below = max(ind - 1, 0);
    int above = min(ind, 62);
    float cdf0 = R.cdf[below], cdf1 = R.cdf[above];
    float bin0 = R.bins[below], bin1 = R.bins[above];
    float denom = cdf1 - cdf0;
    if (denom < 1e-5f) denom = 1.0f;
    float t = (u - cdf0) / denom;
    const float nz = bin0 + t * (bin1 - bin0);

    const float nsig = density_eval(ox + dx * nz, oy + dy * nz, oz + dz * nz, W1, b1, w_sigma, bsig);
    R.nz[lane] = nz;
    __syncthreads();

    // ---- stable merge (matches stable argsort of [z_vals, new_z]) ----
    int posO = lane, posN = lane;
    for (int j = 0; j < 64; ++j) posO += (R.nz[j] < z)  ? 1 : 0;
    for (int i = 0; i < 64; ++i) posN += (R.z[i] <= nz) ? 1 : 0;
    R.zall[posO] = z;   R.sall[posO] = sig;
    R.zall[posN] = nz;  R.sall[posN] = nsig;
    __syncthreads();

    // ---- final compositing over 128 samples: 2 per lane ----
    const int e0 = lane * 2, e1 = lane * 2 + 1;
    float za = R.zall[e0], zb = R.zall[e1];
    float zc = (lane < 63) ? R.zall[e1 + 1] : 0.0f;
    float d0 = zb - za;
    float d1 = (lane < 63) ? (zc - zb) : sample_dist;
    float sa = R.sall[e0], sb = R.sall[e1];
    float ea = expf(-d0 * sa), eb = expf(-d1 * sb);
    float a0 = 1.0f - ea, a1 = 1.0f - eb;
    float T0 = ea + 1e-15f, T1 = eb + 1e-15f;

    // pair product, wave scan -> per-element exclusive prefix
    float P = T0 * T1;
    float ppin = P;
    #pragma unroll
    for (int off = 1; off < 64; off <<= 1) {
        float v = __shfl_up(ppin, off);
        if (lane >= off) ppin *= v;
    }
    float pex = __shfl_up(ppin, 1);
    if (lane == 0) pex = 1.0f;
    float w0 = a0 * pex;
    float w1 = a1 * pex * T0;

    // color MLP for both samples (dirs = raw rays_d)
    float r0, g0, c0, r1, g1, c1;
    color_eval(ox + dx * za, oy + dy * za, oz + dz * za, dx, dy, dz, Wc1, bc1, Wc2, bc2, r0, g0, c0);
    color_eval(ox + dx * zb, oy + dy * zb, oz + dz * zb, dx, dy, dz, Wc1, bc1, Wc2, bc2, r1, g1, c1);

    float accR = w0 * r0 + w1 * r1;
    float accG = w0 * g0 + w1 * g1;
    float accB = w0 * c0 + w1 * c1;
    float accW = w0 + w1;
    #pragma unroll
    for (int off = 32; off > 0; off >>= 1) {
        accR += __shfl_xor(accR, off);
        accG += __shfl_xor(accG, off);
        accB += __shfl_xor(accB, off);
        accW += __shfl_xor(accW, off);
    }
    if (lane == 0 && valid) {
        out[ray * 3 + 0] = accR + (1.0f - accW);   // white background
        out[ray * 3 + 1] = accG + (1.0f - accW);
        out[ray * 3 + 2] = accB + (1.0f - accW);
    }
}

extern "C" void kernel_launch(void* const* d_in, const int* in_sizes, int n_in,
                              void* d_out, int out_size, void* d_ws, size_t ws_size,
                              hipStream_t stream) {
    const float* rays_o  = (const float*)d_in[0];
    const float* rays_d  = (const float*)d_in[1];
    const float* W1      = (const float*)d_in[2];
    const float* b1      = (const float*)d_in[3];
    const float* w_sigma = (const float*)d_in[4];
    const float* b_sigma = (const float*)d_in[5];
    const float* Wc1     = (const float*)d_in[6];
    const float* bc1     = (const float*)d_in[7];
    const float* Wc2     = (const float*)d_in[8];
    const float* bc2     = (const float*)d_in[9];
    float* out = (float*)d_out;

    int nrays = in_sizes[0] / 3;
    int blocks = (nrays + 3) / 4;
    nerf_render_kernel<<<blocks, 256, 0, stream>>>(
        rays_o, rays_d, W1, b1, w_sigma, b_sigma, Wc1, bc1, Wc2, bc2, out, nrays);
}

// Round 2
// 131.675 us; speedup vs baseline: 1.0970x; 1.0970x over previous
//
#include <hip/hip_runtime.h>
#include <math.h>

// NeRF renderer: 16384 rays; 64 coarse + 64 fine samples; HIDDEN=64.
// One wave per ray, 4 rays per 256-thread block.
// Key idea: along a ray, p = o + d*z, so every hidden unit's pre-activation is
// affine in z:  h_j(z) = relu(A_j + z*B_j).  A_j/B_j are computed once per ray
// (lane j owns hidden unit j) and stored in per-wave LDS tables; the per-sample
// MLP loops then do 1 fma per hidden unit (density) / fused 2-sample color.

__device__ __forceinline__ float softplus_f(float x) {
    // identical to jax.nn.softplus = logaddexp(x, 0)
    return fmaxf(x, 0.0f) + log1pf(expf(-fabsf(x)));
}

struct __align__(16) RayLds {
    float4 dTab[64];   // {dA_j, dB_j, w_sigma_j, 0}
    float4 cTab[64];   // {cA_j, cB_j, Wc2[j][0], Wc2[j][1]}
    float  cW2b[64];   // Wc2[j][2]
    float  z[64];      // coarse z
    float  nz[64];     // fine z
    float  cdf[64];    // cdf[0..63] (cdf[63]=1.0, never selected)
    float  bins[64];   // z_mid (bins[63] unused)
    float  zall[128];  // merged z
    float  sall[128];  // merged sigma
};

__device__ __forceinline__ float density_eval2(float zv, const float4* __restrict__ dTab, float bsig) {
    float acc = bsig;
    #pragma unroll 16
    for (int j = 0; j < 64; ++j) {
        float4 t = dTab[j];                        // LDS broadcast read (b128)
        float h = fmaxf(fmaf(zv, t.y, t.x), 0.0f); // relu(A + z*B)
        acc = fmaf(h, t.z, acc);
    }
    return softplus_f(acc);
}

__global__ __launch_bounds__(256, 4) void nerf_render_kernel(
    const float* __restrict__ rays_o, const float* __restrict__ rays_d,
    const float* __restrict__ W1, const float* __restrict__ b1,
    const float* __restrict__ w_sigma, const float* __restrict__ b_sigma,
    const float* __restrict__ Wc1, const float* __restrict__ bc1,
    const float* __restrict__ Wc2, const float* __restrict__ bc2,
    float* __restrict__ out, int nrays)
{
    __shared__ RayLds L[4];
    const int wave = threadIdx.x >> 6;
    const int lane = threadIdx.x & 63;
    int ray = blockIdx.x * 4 + wave;
    const bool valid = ray < nrays;
    if (!valid) ray = 0;
    RayLds& R = L[wave];

    const float ox = rays_o[ray * 3 + 0], oy = rays_o[ray * 3 + 1], oz = rays_o[ray * 3 + 2];
    const float dx = rays_d[ray * 3 + 0], dy = rays_d[ray * 3 + 1], dz = rays_d[ray * 3 + 2];
    const float bsig = b_sigma[0];
    const float bc2r = bc2[0], bc2g = bc2[1], bc2b = bc2[2];

    // ---- per-ray affine coefficient tables (lane j = hidden unit j) ----
    {
        const int j = lane;
        float w0 = W1[j], w1 = W1[64 + j], w2 = W1[128 + j];
        float dA = fmaf(ox, w0, fmaf(oy, w1, fmaf(oz, w2, b1[j])));
        float dB = fmaf(dx, w0, fmaf(dy, w1, dz * w2));
        R.dTab[j] = make_float4(dA, dB, w_sigma[j], 0.0f);

        float c0 = Wc1[j], c1 = Wc1[64 + j], c2 = Wc1[128 + j];
        float c3 = Wc1[192 + j], c4 = Wc1[256 + j], c5 = Wc1[320 + j];
        // dirs input == rays_d (constant along ray): fold into A
        float cA = fmaf(ox, c0, fmaf(oy, c1, fmaf(oz, c2,
                   fmaf(dx, c3, fmaf(dy, c4, fmaf(dz, c5, bc1[j]))))));
        float cB = fmaf(dx, c0, fmaf(dy, c1, dz * c2));
        R.cTab[j] = make_float4(cA, cB, Wc2[3 * j], Wc2[3 * j + 1]);
        R.cW2b[j] = Wc2[3 * j + 2];
    }

    // ---- near/far vs cube [-1,1]^3 (slab test, faithful incl. +1e-15) ----
    float ivx = 1.0f / (dx + 1e-15f), ivy = 1.0f / (dy + 1e-15f), ivz = 1.0f / (dz + 1e-15f);
    float tax = (-1.0f - ox) * ivx, tbx = (1.0f - ox) * ivx;
    float tay = (-1.0f - oy) * ivy, tby = (1.0f - oy) * ivy;
    float taz = (-1.0f - oz) * ivz, tbz = (1.0f - oz) * ivz;
    float nearv = fmaxf(fmaxf(fminf(tax, tbx), fminf(tay, tby)), fminf(taz, tbz));
    float farv  = fminf(fminf(fmaxf(tax, tbx), fmaxf(tay, tby)), fmaxf(taz, tbz));
    if (farv < nearv) { nearv = 1e9f; farv = 1e9f; }
    nearv = fmaxf(nearv, 0.5f);
    const float sample_dist = (farv - nearv) * (1.0f / 64.0f);

    __syncthreads();   // tabs visible to all lanes of the wave

    // ---- coarse samples: z_i = near + (far-near)*i/63, density ----
    const float z = nearv + (farv - nearv) * ((float)lane * (1.0f / 63.0f));
    const float sig = density_eval2(z, R.dTab, bsig);
    R.z[lane] = z;

    float znext = __shfl_down(z, 1);
    float delta = (lane < 63) ? (znext - z) : sample_dist;
    float e = expf(-delta * sig);
    float alpha = 1.0f - e;
    float T = e + 1e-15f;               // 1 - alpha + 1e-15

    // exclusive prefix-product of T across the wave
    float pincl = T;
    #pragma unroll
    for (int off = 1; off < 64; off <<= 1) {
        float v = __shfl_up(pincl, off);
        if (lane >= off) pincl *= v;
    }
    float pexcl = __shfl_up(pincl, 1);
    if (lane == 0) pexcl = 1.0f;
    const float wgt = alpha * pexcl;    // coarse weights

    // ---- pdf/cdf over weights[1..62]; bins = z_mid ----
    float val = (lane >= 1 && lane <= 62) ? (wgt + 1e-5f) : 0.0f;
    float sincl = val;
    #pragma unroll
    for (int off = 1; off < 64; off <<= 1) {
        float v = __shfl_up(sincl, off);
        if (lane >= off) sincl += v;
    }
    const float wsum = __shfl(sincl, 63);
    R.cdf[lane]  = sincl / wsum;        // lane63 -> 1.0 (count-safe sentinel)
    R.bins[lane] = z + 0.5f * delta;    // lane63 unused
    __syncthreads();

    // ---- deterministic inverse-CDF sampling: u_k = (k+0.5)/64 ----
    const float u = ((float)lane + 0.5f) * (1.0f / 64.0f);
    int ind = 0;
    const float4* cdf4 = (const float4*)R.cdf;
    #pragma unroll
    for (int q = 0; q < 16; ++q) {      // searchsorted-right over 63 entries (+1.0 sentinel)
        float4 v = cdf4[q];
        ind += (v.x <= u) ? 1 : 0;
        ind += (v.y <= u) ? 1 : 0;
        ind += (v.z <= u) ? 1 : 0;
        ind += (v.w <= u) ? 1 : 0;
    }
    int below = max(ind - 1, 0);
    int above = min(ind, 62);
    float cdf0 = R.cdf[below], cdf1 = R.cdf[above];
    float bin0 = R.bins[below], bin1 = R.bins[above];
    float denom = cdf1 - cdf0;
    if (denom < 1e-5f) denom = 1.0f;
    float t = (u - cdf0) / denom;
    const float nz = bin0 + t * (bin1 - bin0);

    const float nsig = density_eval2(nz, R.dTab, bsig);
    R.nz[lane] = nz;
    __syncthreads();

    // ---- stable merge (matches stable argsort of [z_vals, new_z]) ----
    int posO = lane, posN = lane;
    const float4* nz4 = (const float4*)R.nz;
    const float4* z4  = (const float4*)R.z;
    #pragma unroll
    for (int q = 0; q < 16; ++q) {
        float4 a = nz4[q];
        posO += (a.x < z) ? 1 : 0;
        posO += (a.y < z) ? 1 : 0;
        posO += (a.z < z) ? 1 : 0;
        posO += (a.w < z) ? 1 : 0;
        float4 b = z4[q];
        posN += (b.x <= nz) ? 1 : 0;
        posN += (b.y <= nz) ? 1 : 0;
        posN += (b.z <= nz) ? 1 : 0;
        posN += (b.w <= nz) ? 1 : 0;
    }
    R.zall[posO] = z;   R.sall[posO] = sig;
    R.zall[posN] = nz;  R.sall[posN] = nsig;
    __syncthreads();

    // ---- final compositing over 128 samples: 2 per lane ----
    float2 zz = ((const float2*)R.zall)[lane];
    float2 ss = ((const float2*)R.sall)[lane];
    float za = zz.x, zb = zz.y;
    float zc = __shfl_down(za, 1);      // zall[2*lane+2]
    float d0 = zb - za;
    float d1 = (lane < 63) ? (zc - zb) : sample_dist;
    float ea = expf(-d0 * ss.x), eb = expf(-d1 * ss.y);
    float a0 = 1.0f - ea, a1 = 1.0f - eb;
    float T0 = ea + 1e-15f, T1 = eb + 1e-15f;

    // pair product, wave scan -> per-element exclusive prefix
    float ppin = T0 * T1;
    #pragma unroll
    for (int off = 1; off < 64; off <<= 1) {
        float v = __shfl_up(ppin, off);
        if (lane >= off) ppin *= v;
    }
    float pex = __shfl_up(ppin, 1);
    if (lane == 0) pex = 1.0f;
    float w0 = a0 * pex;
    float w1 = a1 * pex * T0;

    // color MLP for both samples, fused layer1+layer2: h = relu(A + z*B)
    float ar0 = bc2r, ag0 = bc2g, ab0 = bc2b;
    float ar1 = bc2r, ag1 = bc2g, ab1 = bc2b;
    const float4* cT = R.cTab;
    const float*  wb2 = R.cW2b;
    #pragma unroll 16
    for (int j = 0; j < 64; ++j) {
        float4 q = cT[j];               // {cA, cB, w2r, w2g} broadcast
        float wb = wb2[j];
        float h0 = fmaxf(fmaf(za, q.y, q.x), 0.0f);
        float h1 = fmaxf(fmaf(zb, q.y, q.x), 0.0f);
        ar0 = fmaf(h0, q.z, ar0); ag0 = fmaf(h0, q.w, ag0); ab0 = fmaf(h0, wb, ab0);
        ar1 = fmaf(h1, q.z, ar1); ag1 = fmaf(h1, q.w, ag1); ab1 = fmaf(h1, wb, ab1);
    }
    float r0 = 1.0f / (1.0f + expf(-ar0));
    float g0 = 1.0f / (1.0f + expf(-ag0));
    float c0 = 1.0f / (1.0f + expf(-ab0));
    float r1 = 1.0f / (1.0f + expf(-ar1));
    float g1 = 1.0f / (1.0f + expf(-ag1));
    float c1 = 1.0f / (1.0f + expf(-ab1));

    float accR = w0 * r0 + w1 * r1;
    float accG = w0 * g0 + w1 * g1;
    float accB = w0 * c0 + w1 * c1;
    float accW = w0 + w1;
    #pragma unroll
    for (int off = 32; off > 0; off >>= 1) {
        accR += __shfl_xor(accR, off);
        accG += __shfl_xor(accG, off);
        accB += __shfl_xor(accB, off);
        accW += __shfl_xor(accW, off);
    }
    if (lane == 0 && valid) {
        out[ray * 3 + 0] = accR + (1.0f - accW);   // white background
        out[ray * 3 + 1] = accG + (1.0f - accW);
        out[ray * 3 + 2] = accB + (1.0f - accW);
    }
}

extern "C" void kernel_launch(void* const* d_in, const int* in_sizes, int n_in,
                              void* d_out, int out_size, void* d_ws, size_t ws_size,
                              hipStream_t stream) {
    const float* rays_o  = (const float*)d_in[0];
    const float* rays_d  = (const float*)d_in[1];
    const float* W1      = (const float*)d_in[2];
    const float* b1      = (const float*)d_in[3];
    const float* w_sigma = (const float*)d_in[4];
    const float* b_sigma = (const float*)d_in[5];
    const float* Wc1     = (const float*)d_in[6];
    const float* bc1     = (const float*)d_in[7];
    const float* Wc2     = (const float*)d_in[8];
    const float* bc2     = (const float*)d_in[9];
    float* out = (float*)d_out;

    int nrays = in_sizes[0] / 3;
    int blocks = (nrays + 3) / 4;
    nerf_render_kernel<<<blocks, 256, 0, stream>>>(
        rays_o, rays_d, W1, b1, w_sigma, b_sigma, Wc1, bc1, Wc2, bc2, out, nrays);
}

// Round 5
// 105.406 us; speedup vs baseline: 1.3704x; 1.2492x over previous
//
#include <hip/hip_runtime.h>
#include <math.h>

// NeRF renderer: 16384 rays; 64 coarse + 64 fine samples; HIDDEN=64.
// One wave per ray, 4 waves (rays) per 256-thread block, no block barriers
// (all LDS state is wave-private; DS ops are wave-ordered on CDNA).
// h_j(z) = relu(A_j + z*B_j) affine-in-z trick; tables in LDS, broadcast reads.

#define EXP2F(x) __builtin_amdgcn_exp2f(x)
#define LOG2F(x) __builtin_amdgcn_logf(x)
#define RCPF(x)  __builtin_amdgcn_rcpf(x)
#define WSYNC()  __builtin_amdgcn_wave_barrier()

__device__ __forceinline__ float fast_exp(float x)   { return EXP2F(x * 1.44269504088896340736f); }
__device__ __forceinline__ float fast_sigmoid(float x) { return RCPF(1.0f + EXP2F(-x * 1.44269504088896340736f)); }
__device__ __forceinline__ float fast_softplus(float x) {
    // max(x,0) + log1p(exp(-|x|)), log1p via v_log_f32 (abs err ~1e-7, fine here)
    float y = EXP2F(-fabsf(x) * 1.44269504088896340736f);
    return fmaxf(x, 0.0f) + 0.6931471805599453f * LOG2F(1.0f + y);
}

struct __align__(16) RayLds {
    float2 dAB[64];    // density {A,B} per unit        (512B, 16-aligned)
    float  dws[64];    // w_sigma                       (256B)
    float2 cAB[64];    // color {A,B} per unit          (512B)
    float  cwr[64];    // Wc2[:,0]
    float  cwg[64];    // Wc2[:,1]
    float  cwb[64];    // Wc2[:,2]
    float  z[64];      // coarse z (sorted)
    float  nz[64];     // fine z (sorted by construction)
    float  cdf[64];    // cdf[0..62], cdf[63]=~1.0 sentinel
    float  bins[64];   // z_mid[0..62]
    float  zall[128];  // merged z
    float  sall[128];  // merged sigma
};  // 4096 B per wave

// count of arr[i] < key over sorted arr[64]; 7 gather reads, branchless
__device__ __forceinline__ int count_lt(const float* __restrict__ arr, float key) {
    int c = 0;
    #pragma unroll
    for (int s = 32; s >= 1; s >>= 1)
        c += (arr[c + s - 1] < key) ? s : 0;
    c += (arr[c] < key) ? 1 : 0;     // promotes 63->64 iff all < key
    return c;
}
__device__ __forceinline__ int count_le(const float* __restrict__ arr, float key) {
    int c = 0;
    #pragma unroll
    for (int s = 32; s >= 1; s >>= 1)
        c += (arr[c + s - 1] <= key) ? s : 0;
    c += (arr[c] <= key) ? 1 : 0;
    return c;
}

__device__ __forceinline__ float density_eval(float zv, const RayLds& R, float bsig) {
    const float4* ab = (const float4*)R.dAB;   // {A0,B0,A1,B1} per read
    const float4* ws = (const float4*)R.dws;
    float a0 = 0.0f, a1 = 0.0f, a2 = 0.0f, a3 = 0.0f;
    #pragma unroll
    for (int g = 0; g < 16; ++g) {
        float4 p0 = ab[2 * g];
        float4 p1 = ab[2 * g + 1];
        float4 w  = ws[g];
        float h0 = fmaxf(fmaf(zv, p0.y, p0.x), 0.0f);
        float h1 = fmaxf(fmaf(zv, p0.w, p0.z), 0.0f);
        float h2 = fmaxf(fmaf(zv, p1.y, p1.x), 0.0f);
        float h3 = fmaxf(fmaf(zv, p1.w, p1.z), 0.0f);
        a0 = fmaf(h0, w.x, a0);
        a1 = fmaf(h1, w.y, a1);
        a2 = fmaf(h2, w.z, a2);
        a3 = fmaf(h3, w.w, a3);
    }
    return fast_softplus(((a0 + a1) + (a2 + a3)) + bsig);
}

__global__ __launch_bounds__(256, 6) void nerf_render_kernel(
    const float* __restrict__ rays_o, const float* __restrict__ rays_d,
    const float* __restrict__ W1, const float* __restrict__ b1,
    const float* __restrict__ w_sigma, const float* __restrict__ b_sigma,
    const float* __restrict__ Wc1, const float* __restrict__ bc1,
    const float* __restrict__ Wc2, const float* __restrict__ bc2,
    float* __restrict__ out, int nrays)
{
    __shared__ RayLds L[4];
    const int wave = threadIdx.x >> 6;
    const int lane = threadIdx.x & 63;
    int ray = blockIdx.x * 4 + wave;
    const bool valid = ray < nrays;
    if (!valid) ray = 0;
    RayLds& R = L[wave];

    const float ox = rays_o[ray * 3 + 0], oy = rays_o[ray * 3 + 1], oz = rays_o[ray * 3 + 2];
    const float dx = rays_d[ray * 3 + 0], dy = rays_d[ray * 3 + 1], dz = rays_d[ray * 3 + 2];
    const float bsig = b_sigma[0];
    const float bc2r = bc2[0], bc2g = bc2[1], bc2b = bc2[2];

    // ---- per-ray affine tables (lane j = hidden unit j) ----
    {
        const int j = lane;
        float w0 = W1[j], w1 = W1[64 + j], w2 = W1[128 + j];
        float dA = fmaf(ox, w0, fmaf(oy, w1, fmaf(oz, w2, b1[j])));
        float dB = fmaf(dx, w0, fmaf(dy, w1, dz * w2));
        R.dAB[j] = make_float2(dA, dB);
        R.dws[j] = w_sigma[j];

        float c0 = Wc1[j], c1 = Wc1[64 + j], c2 = Wc1[128 + j];
        float c3 = Wc1[192 + j], c4 = Wc1[256 + j], c5 = Wc1[320 + j];
        float cA = fmaf(ox, c0, fmaf(oy, c1, fmaf(oz, c2,
                   fmaf(dx, c3, fmaf(dy, c4, fmaf(dz, c5, bc1[j]))))));
        float cB = fmaf(dx, c0, fmaf(dy, c1, dz * c2));
        R.cAB[j] = make_float2(cA, cB);
        R.cwr[j] = Wc2[3 * j + 0];
        R.cwg[j] = Wc2[3 * j + 1];
        R.cwb[j] = Wc2[3 * j + 2];
    }

    // ---- near/far vs cube [-1,1]^3 ----
    float ivx = RCPF(dx + 1e-15f), ivy = RCPF(dy + 1e-15f), ivz = RCPF(dz + 1e-15f);
    float tax = (-1.0f - ox) * ivx, tbx = (1.0f - ox) * ivx;
    float tay = (-1.0f - oy) * ivy, tby = (1.0f - oy) * ivy;
    float taz = (-1.0f - oz) * ivz, tbz = (1.0f - oz) * ivz;
    float nearv = fmaxf(fmaxf(fminf(tax, tbx), fminf(tay, tby)), fminf(taz, tbz));
    float farv  = fminf(fminf(fmaxf(tax, tbx), fmaxf(tay, tby)), fmaxf(taz, tbz));
    if (farv < nearv) { nearv = 1e9f; farv = 1e9f; }
    nearv = fmaxf(nearv, 0.5f);
    const float sample_dist = (farv - nearv) * (1.0f / 64.0f);

    WSYNC();   // tables visible within wave (DS wave-ordered)

    // ---- coarse pass ----
    const float z = nearv + (farv - nearv) * ((float)lane * (1.0f / 63.0f));
    const float sig = density_eval(z, R, bsig);
    R.z[lane] = z;

    float znext = __shfl_down(z, 1);
    float delta = (lane < 63) ? (znext - z) : sample_dist;
    float e = fast_exp(-delta * sig);
    float alpha = 1.0f - e;
    float T = e + 1e-15f;

    float pincl = T;
    #pragma unroll
    for (int off = 1; off < 64; off <<= 1) {
        float v = __shfl_up(pincl, off);
        if (lane >= off) pincl *= v;
    }
    float pexcl = __shfl_up(pincl, 1);
    if (lane == 0) pexcl = 1.0f;
    const float wgt = alpha * pexcl;

    // ---- pdf/cdf over weights[1..62] ----
    float val = (lane >= 1 && lane <= 62) ? (wgt + 1e-5f) : 0.0f;
    float sincl = val;
    #pragma unroll
    for (int off = 1; off < 64; off <<= 1) {
        float v = __shfl_up(sincl, off);
        if (lane >= off) sincl += v;
    }
    const float rws = RCPF(__shfl(sincl, 63));
    R.cdf[lane]  = sincl * rws;        // lane63 ≈ 1.0 sentinel (> u_max)
    R.bins[lane] = z + 0.5f * delta;
    WSYNC();

    // ---- inverse-CDF sampling, u_k = (k+0.5)/64, searchsorted-right ----
    const float u = ((float)lane + 0.5f) * (1.0f / 64.0f);
    int ind = count_le(R.cdf, u);
    int below = max(ind - 1, 0);
    int above = min(ind, 62);
    float cdf0 = R.cdf[below], cdf1 = R.cdf[above];
    float bin0 = R.bins[below], bin1 = R.bins[above];
    float denom = cdf1 - cdf0;
    if (denom < 1e-5f) denom = 1.0f;
    float t = (u - cdf0) * RCPF(denom);
    const float nz = fmaf(t, bin1 - bin0, bin0);

    const float nsig = density_eval(nz, R, bsig);
    R.nz[lane] = nz;
    WSYNC();

    // ---- stable merge via binary ranks (both arrays sorted) ----
    int posO = lane + count_lt(R.nz, z);
    int posN = lane + count_le(R.z, nz);
    R.zall[posO] = z;   R.sall[posO] = sig;
    R.zall[posN] = nz;  R.sall[posN] = nsig;
    WSYNC();

    // ---- final compositing: 2 samples per lane ----
    float2 zz = ((const float2*)R.zall)[lane];
    float2 ss = ((const float2*)R.sall)[lane];
    float za = zz.x, zb = zz.y;
    float zc = __shfl_down(za, 1);
    float d0 = zb - za;
    float d1 = (lane < 63) ? (zc - zb) : sample_dist;
    float ea = fast_exp(-d0 * ss.x), eb = fast_exp(-d1 * ss.y);
    float a0 = 1.0f - ea, a1 = 1.0f - eb;
    float T0 = ea + 1e-15f, T1 = eb + 1e-15f;

    float ppin = T0 * T1;
    #pragma unroll
    for (int off = 1; off < 64; off <<= 1) {
        float v = __shfl_up(ppin, off);
        if (lane >= off) ppin *= v;
    }
    float pex = __shfl_up(ppin, 1);
    if (lane == 0) pex = 1.0f;
    float w0 = a0 * pex;
    float w1 = a1 * pex * T0;

    // ---- color MLP, both samples fused ----
    float ar0 = 0.0f, ag0 = 0.0f, ab0 = 0.0f;
    float ar1 = 0.0f, ag1 = 0.0f, ab1 = 0.0f;
    const float4* cab = (const float4*)R.cAB;
    const float4* wr4 = (const float4*)R.cwr;
    const float4* wg4 = (const float4*)R.cwg;
    const float4* wb4 = (const float4*)R.cwb;
    #pragma unroll
    for (int g = 0; g < 16; ++g) {
        float4 p0 = cab[2 * g];
        float4 p1 = cab[2 * g + 1];
        float4 wr = wr4[g], wg = wg4[g], wb = wb4[g];
        float h0, h1;
        h0 = fmaxf(fmaf(za, p0.y, p0.x), 0.0f);
        h1 = fmaxf(fmaf(zb, p0.y, p0.x), 0.0f);
        ar0 = fmaf(h0, wr.x, ar0); ag0 = fmaf(h0, wg.x, ag0); ab0 = fmaf(h0, wb.x, ab0);
        ar1 = fmaf(h1, wr.x, ar1); ag1 = fmaf(h1, wg.x, ag1); ab1 = fmaf(h1, wb.x, ab1);
        h0 = fmaxf(fmaf(za, p0.w, p0.z), 0.0f);
        h1 = fmaxf(fmaf(zb, p0.w, p0.z), 0.0f);
        ar0 = fmaf(h0, wr.y, ar0); ag0 = fmaf(h0, wg.y, ag0); ab0 = fmaf(h0, wb.y, ab0);
        ar1 = fmaf(h1, wr.y, ar1); ag1 = fmaf(h1, wg.y, ag1); ab1 = fmaf(h1, wb.y, ab1);
        h0 = fmaxf(fmaf(za, p1.y, p1.x), 0.0f);
        h1 = fmaxf(fmaf(zb, p1.y, p1.x), 0.0f);
        ar0 = fmaf(h0, wr.z, ar0); ag0 = fmaf(h0, wg.z, ag0); ab0 = fmaf(h0, wb.z, ab0);
        ar1 = fmaf(h1, wr.z, ar1); ag1 = fmaf(h1, wg.z, ag1); ab1 = fmaf(h1, wb.z, ab1);
        h0 = fmaxf(fmaf(za, p1.w, p1.z), 0.0f);
        h1 = fmaxf(fmaf(zb, p1.w, p1.z), 0.0f);
        ar0 = fmaf(h0, wr.w, ar0); ag0 = fmaf(h0, wg.w, ag0); ab0 = fmaf(h0, wb.w, ab0);
        ar1 = fmaf(h1, wr.w, ar1); ag1 = fmaf(h1, wg.w, ag1); ab1 = fmaf(h1, wb.w, ab1);
    }
    float r0 = fast_sigmoid(ar0 + bc2r), g0 = fast_sigmoid(ag0 + bc2g), c0 = fast_sigmoid(ab0 + bc2b);
    float r1 = fast_sigmoid(ar1 + bc2r), g1 = fast_sigmoid(ag1 + bc2g), c1 = fast_sigmoid(ab1 + bc2b);

    float accR = w0 * r0 + w1 * r1;
    float accG = w0 * g0 + w1 * g1;
    float accB = w0 * c0 + w1 * c1;
    float accW = w0 + w1;
    #pragma unroll
    for (int off = 32; off > 0; off >>= 1) {
        accR += __shfl_xor(accR, off);
        accG += __shfl_xor(accG, off);
        accB += __shfl_xor(accB, off);
        accW += __shfl_xor(accW, off);
    }
    if (lane == 0 && valid) {
        out[ray * 3 + 0] = accR + (1.0f - accW);
        out[ray * 3 + 1] = accG + (1.0f - accW);
        out[ray * 3 + 2] = accB + (1.0f - accW);
    }
}

extern "C" void kernel_launch(void* const* d_in, const int* in_sizes, int n_in,
                              void* d_out, int out_size, void* d_ws, size_t ws_size,
                              hipStream_t stream) {
    const float* rays_o  = (const float*)d_in[0];
    const float* rays_d  = (const float*)d_in[1];
    const float* W1      = (const float*)d_in[2];
    const float* b1      = (const float*)d_in[3];
    const float* w_sigma = (const float*)d_in[4];
    const float* b_sigma = (const float*)d_in[5];
    const float* Wc1     = (const float*)d_in[6];
    const float* bc1     = (const float*)d_in[7];
    const float* Wc2     = (const float*)d_in[8];
    const float* bc2     = (const float*)d_in[9];
    float* out = (float*)d_out;

    int nrays = in_sizes[0] / 3;
    int blocks = (nrays + 3) / 4;
    nerf_render_kernel<<<blocks, 256, 0, stream>>>(
        rays_o, rays_d, W1, b1, w_sigma, b_sigma, Wc1, bc1, Wc2, bc2, out, nrays);
}

// Round 6
// 103.517 us; speedup vs baseline: 1.3954x; 1.0182x over previous
//
#include <hip/hip_runtime.h>
#include <math.h>

// NeRF renderer: 16384 rays; 64 coarse + 64 fine samples; HIDDEN=64.
// One wave per ray, 4 waves (rays) per 256-thread block, wave-private LDS,
// no block barriers. h_j(z) = relu(A_j + z*B_j) affine-in-z trick.

#define EXP2F(x) __builtin_amdgcn_exp2f(x)
#define LOG2F(x) __builtin_amdgcn_logf(x)
#define RCPF(x)  __builtin_amdgcn_rcpf(x)
#define WSYNC()  __builtin_amdgcn_wave_barrier()

__device__ __forceinline__ float fast_exp(float x)   { return EXP2F(x * 1.44269504088896340736f); }
__device__ __forceinline__ float fast_sigmoid(float x) { return RCPF(1.0f + EXP2F(-x * 1.44269504088896340736f)); }
__device__ __forceinline__ float fast_softplus(float x) {
    float y = EXP2F(-fabsf(x) * 1.44269504088896340736f);
    return fmaxf(x, 0.0f) + 0.6931471805599453f * LOG2F(1.0f + y);
}

struct __align__(16) RayLds {
    float2 dAB[64];    // density {A,B}
    float  dws[64];    // w_sigma
    float2 cAB[64];    // color {A,B}
    float  cwr[64];    // Wc2[:,0]
    float  cwg[64];    // Wc2[:,1]
    float  cwb[64];    // Wc2[:,2]
    float  z[64];      // coarse z (sorted)
    float  nz[64];     // fine z (sorted)
    float2 cb[64];     // {cdf, z_mid}; cb[63].x ≈ 1.0 sentinel
    float2 zs[128];    // merged {z, sigma}
};  // 4096 B per wave

// count over sorted arr[64]
__device__ __forceinline__ int count_lt(const float* __restrict__ arr, float key) {
    int c = 0;
    #pragma unroll
    for (int s = 32; s >= 1; s >>= 1)
        c += (arr[c + s - 1] < key) ? s : 0;
    c += (arr[c] < key) ? 1 : 0;
    return c;
}
__device__ __forceinline__ int count_le(const float* __restrict__ arr, float key) {
    int c = 0;
    #pragma unroll
    for (int s = 32; s >= 1; s >>= 1)
        c += (arr[c + s - 1] <= key) ? s : 0;
    c += (arr[c] <= key) ? 1 : 0;
    return c;
}

__device__ __forceinline__ float density_eval(float zv, const RayLds& R, float bsig) {
    const float4* ab = (const float4*)R.dAB;   // {A0,B0,A1,B1}
    const float4* ws = (const float4*)R.dws;
    float a0 = 0.0f, a1 = 0.0f, a2 = 0.0f, a3 = 0.0f;
    #pragma unroll
    for (int g = 0; g < 16; ++g) {
        float4 p0 = ab[2 * g];
        float4 p1 = ab[2 * g + 1];
        float4 w  = ws[g];
        float h0 = fmaxf(fmaf(zv, p0.y, p0.x), 0.0f);
        float h1 = fmaxf(fmaf(zv, p0.w, p0.z), 0.0f);
        float h2 = fmaxf(fmaf(zv, p1.y, p1.x), 0.0f);
        float h3 = fmaxf(fmaf(zv, p1.w, p1.z), 0.0f);
        a0 = fmaf(h0, w.x, a0);
        a1 = fmaf(h1, w.y, a1);
        a2 = fmaf(h2, w.z, a2);
        a3 = fmaf(h3, w.w, a3);
    }
    return fast_softplus(((a0 + a1) + (a2 + a3)) + bsig);
}

__global__ __launch_bounds__(256, 4) void nerf_render_kernel(
    const float* __restrict__ rays_o, const float* __restrict__ rays_d,
    const float* __restrict__ W1, const float* __restrict__ b1,
    const float* __restrict__ w_sigma, const float* __restrict__ b_sigma,
    const float* __restrict__ Wc1, const float* __restrict__ bc1,
    const float* __restrict__ Wc2, const float* __restrict__ bc2,
    float* __restrict__ out, int nrays)
{
    __shared__ RayLds L[4];
    const int wave = threadIdx.x >> 6;
    const int lane = threadIdx.x & 63;
    int ray = blockIdx.x * 4 + wave;
    const bool valid = ray < nrays;
    if (!valid) ray = 0;
    RayLds& R = L[wave];

    const float ox = rays_o[ray * 3 + 0], oy = rays_o[ray * 3 + 1], oz = rays_o[ray * 3 + 2];
    const float dx = rays_d[ray * 3 + 0], dy = rays_d[ray * 3 + 1], dz = rays_d[ray * 3 + 2];
    const float bsig = b_sigma[0];
    const float bc2r = bc2[0], bc2g = bc2[1], bc2b = bc2[2];

    // ---- per-ray affine tables (lane j = hidden unit j) ----
    {
        const int j = lane;
        float w0 = W1[j], w1 = W1[64 + j], w2 = W1[128 + j];
        float dA = fmaf(ox, w0, fmaf(oy, w1, fmaf(oz, w2, b1[j])));
        float dB = fmaf(dx, w0, fmaf(dy, w1, dz * w2));
        R.dAB[j] = make_float2(dA, dB);
        R.dws[j] = w_sigma[j];

        float c0 = Wc1[j], c1 = Wc1[64 + j], c2 = Wc1[128 + j];
        float c3 = Wc1[192 + j], c4 = Wc1[256 + j], c5 = Wc1[320 + j];
        float cA = fmaf(ox, c0, fmaf(oy, c1, fmaf(oz, c2,
                   fmaf(dx, c3, fmaf(dy, c4, fmaf(dz, c5, bc1[j]))))));
        float cB = fmaf(dx, c0, fmaf(dy, c1, dz * c2));
        R.cAB[j] = make_float2(cA, cB);
        R.cwr[j] = Wc2[3 * j + 0];
        R.cwg[j] = Wc2[3 * j + 1];
        R.cwb[j] = Wc2[3 * j + 2];
    }

    // ---- near/far vs cube [-1,1]^3 ----
    float ivx = RCPF(dx + 1e-15f), ivy = RCPF(dy + 1e-15f), ivz = RCPF(dz + 1e-15f);
    float tax = (-1.0f - ox) * ivx, tbx = (1.0f - ox) * ivx;
    float tay = (-1.0f - oy) * ivy, tby = (1.0f - oy) * ivy;
    float taz = (-1.0f - oz) * ivz, tbz = (1.0f - oz) * ivz;
    float nearv = fmaxf(fmaxf(fminf(tax, tbx), fminf(tay, tby)), fminf(taz, tbz));
    float farv  = fminf(fminf(fmaxf(tax, tbx), fmaxf(tay, tby)), fmaxf(taz, tbz));
    if (farv < nearv) { nearv = 1e9f; farv = 1e9f; }
    nearv = fmaxf(nearv, 0.5f);
    const float sample_dist = (farv - nearv) * (1.0f / 64.0f);
    const float step = (farv - nearv) * (1.0f / 63.0f);   // coarse spacing (const along ray)

    WSYNC();   // tables visible within wave (DS wave-ordered)

    // ---- coarse pass ----
    const float z = fmaf((float)lane, step, nearv);
    const float sig = density_eval(z, R, bsig);
    R.z[lane] = z;

    float delta = (lane < 63) ? step : sample_dist;
    float e = fast_exp(-delta * sig);
    float alpha = 1.0f - e;
    float T = e + 1e-15f;

    float pincl = T;
    #pragma unroll
    for (int off = 1; off < 64; off <<= 1) {
        float v = __shfl_up(pincl, off);
        if (lane >= off) pincl *= v;
    }
    float pexcl = __shfl_up(pincl, 1);
    if (lane == 0) pexcl = 1.0f;
    const float wgt = alpha * pexcl;

    // ---- pdf/cdf over weights[1..62] ----
    float val = (lane >= 1 && lane <= 62) ? (wgt + 1e-5f) : 0.0f;
    float sincl = val;
    #pragma unroll
    for (int off = 1; off < 64; off <<= 1) {
        float v = __shfl_up(sincl, off);
        if (lane >= off) sincl += v;
    }
    const float rws = RCPF(__shfl(sincl, 63));
    R.cb[lane] = make_float2(sincl * rws, fmaf(0.5f, step, z));   // {cdf, z_mid}
    WSYNC();

    // ---- inverse-CDF sampling, u_k = (k+0.5)/64, searchsorted-right ----
    const float u = ((float)lane + 0.5f) * (1.0f / 64.0f);
    int ind = 0;
    {
        const float2* cb = R.cb;
        #pragma unroll
        for (int s = 32; s >= 1; s >>= 1)
            ind += (cb[ind + s - 1].x <= u) ? s : 0;
        ind += (cb[ind].x <= u) ? 1 : 0;
    }
    int below = max(ind - 1, 0);
    int above = min(ind, 62);
    float2 lo = R.cb[below];
    float2 hi = R.cb[above];
    float denom = hi.x - lo.x;
    if (denom < 1e-5f) denom = 1.0f;
    float t = (u - lo.x) * RCPF(denom);
    const float nz = fmaf(t, hi.y - lo.y, lo.y);

    const float nsig = density_eval(nz, R, bsig);
    R.nz[lane] = nz;
    WSYNC();

    // ---- stable merge via binary ranks (both arrays sorted) ----
    int posO = lane + count_lt(R.nz, z);
    int posN = lane + count_le(R.z, nz);
    R.zs[posO] = make_float2(z, sig);
    R.zs[posN] = make_float2(nz, nsig);
    WSYNC();

    // ---- final compositing: 2 samples per lane ----
    float4 q = ((const float4*)R.zs)[lane];         // {za, sa, zb, sb}
    float za = q.x, sa = q.y, zb = q.z, sb = q.w;
    float zc = R.zs[min(2 * lane + 2, 127)].x;
    float d0 = zb - za;
    float d1 = (lane < 63) ? (zc - zb) : sample_dist;
    float ea = fast_exp(-d0 * sa), eb = fast_exp(-d1 * sb);
    float a0 = 1.0f - ea, a1 = 1.0f - eb;
    float T0 = ea + 1e-15f, T1 = eb + 1e-15f;

    float ppin = T0 * T1;
    #pragma unroll
    for (int off = 1; off < 64; off <<= 1) {
        float v = __shfl_up(ppin, off);
        if (lane >= off) ppin *= v;
    }
    float pex = __shfl_up(ppin, 1);
    if (lane == 0) pex = 1.0f;
    float w0 = a0 * pex;
    float w1 = a1 * pex * T0;

    // ---- color MLP, both samples fused ----
    float ar0 = 0.0f, ag0 = 0.0f, ab0 = 0.0f;
    float ar1 = 0.0f, ag1 = 0.0f, ab1 = 0.0f;
    const float4* cab = (const float4*)R.cAB;
    const float4* wr4 = (const float4*)R.cwr;
    const float4* wg4 = (const float4*)R.cwg;
    const float4* wb4 = (const float4*)R.cwb;
    #pragma unroll
    for (int g = 0; g < 16; ++g) {
        float4 p0 = cab[2 * g];
        float4 p1 = cab[2 * g + 1];
        float4 wr = wr4[g], wg = wg4[g], wb = wb4[g];
        float h0, h1;
        h0 = fmaxf(fmaf(za, p0.y, p0.x), 0.0f);
        h1 = fmaxf(fmaf(zb, p0.y, p0.x), 0.0f);
        ar0 = fmaf(h0, wr.x, ar0); ag0 = fmaf(h0, wg.x, ag0); ab0 = fmaf(h0, wb.x, ab0);
        ar1 = fmaf(h1, wr.x, ar1); ag1 = fmaf(h1, wg.x, ag1); ab1 = fmaf(h1, wb.x, ab1);
        h0 = fmaxf(fmaf(za, p0.w, p0.z), 0.0f);
        h1 = fmaxf(fmaf(zb, p0.w, p0.z), 0.0f);
        ar0 = fmaf(h0, wr.y, ar0); ag0 = fmaf(h0, wg.y, ag0); ab0 = fmaf(h0, wb.y, ab0);
        ar1 = fmaf(h1, wr.y, ar1); ag1 = fmaf(h1, wg.y, ag1); ab1 = fmaf(h1, wb.y, ab1);
        h0 = fmaxf(fmaf(za, p1.y, p1.x), 0.0f);
        h1 = fmaxf(fmaf(zb, p1.y, p1.x), 0.0f);
        ar0 = fmaf(h0, wr.z, ar0); ag0 = fmaf(h0, wg.z, ag0); ab0 = fmaf(h0, wb.z, ab0);
        ar1 = fmaf(h1, wr.z, ar1); ag1 = fmaf(h1, wg.z, ag1); ab1 = fmaf(h1, wb.z, ab1);
        h0 = fmaxf(fmaf(za, p1.w, p1.z), 0.0f);
        h1 = fmaxf(fmaf(zb, p1.w, p1.z), 0.0f);
        ar0 = fmaf(h0, wr.w, ar0); ag0 = fmaf(h0, wg.w, ag0); ab0 = fmaf(h0, wb.w, ab0);
        ar1 = fmaf(h1, wr.w, ar1); ag1 = fmaf(h1, wg.w, ag1); ab1 = fmaf(h1, wb.w, ab1);
    }
    float r0 = fast_sigmoid(ar0 + bc2r), g0 = fast_sigmoid(ag0 + bc2g), c0 = fast_sigmoid(ab0 + bc2b);
    float r1 = fast_sigmoid(ar1 + bc2r), g1 = fast_sigmoid(ag1 + bc2g), c1 = fast_sigmoid(ab1 + bc2b);

    float accR = w0 * r0 + w1 * r1;
    float accG = w0 * g0 + w1 * g1;
    float accB = w0 * c0 + w1 * c1;
    float accW = w0 + w1;
    #pragma unroll
    for (int off = 32; off > 0; off >>= 1) {
        accR += __shfl_xor(accR, off);
        accG += __shfl_xor(accG, off);
        accB += __shfl_xor(accB, off);
        accW += __shfl_xor(accW, off);
    }
    if (lane == 0 && valid) {
        out[ray * 3 + 0] = accR + (1.0f - accW);
        out[ray * 3 + 1] = accG + (1.0f - accW);
        out[ray * 3 + 2] = accB + (1.0f - accW);
    }
}

extern "C" void kernel_launch(void* const* d_in, const int* in_sizes, int n_in,
                              void* d_out, int out_size, void* d_ws, size_t ws_size,
                              hipStream_t stream) {
    const float* rays_o  = (const float*)d_in[0];
    const float* rays_d  = (const float*)d_in[1];
    const float* W1      = (const float*)d_in[2];
    const float* b1      = (const float*)d_in[3];
    const float* w_sigma = (const float*)d_in[4];
    const float* b_sigma = (const float*)d_in[5];
    const float* Wc1     = (const float*)d_in[6];
    const float* bc1     = (const float*)d_in[7];
    const float* Wc2     = (const float*)d_in[8];
    const float* bc2     = (const float*)d_in[9];
    float* out = (float*)d_out;

    int nrays = in_sizes[0] / 3;
    int blocks = (nrays + 3) / 4;
    nerf_render_kernel<<<blocks, 256, 0, stream>>>(
        rays_o, rays_d, W1, b1, w_sigma, b_sigma, Wc1, bc1, Wc2, bc2, out, nrays);
}